// Round 13
// baseline (282.230 us; speedup 1.0000x reference)
//
#include <hip/hip_runtime.h>
#include <cmath>

#define EPSV 1e-8f

typedef __bf16 bf16_t;
typedef __bf16 bf16x8 __attribute__((ext_vector_type(8)));
typedef __bf16 bf16x4 __attribute__((ext_vector_type(4)));
typedef float f32x4 __attribute__((ext_vector_type(4)));

__device__ __forceinline__ void gload16(const void* g, void* l) {
    __builtin_amdgcn_global_load_lds(
        (const __attribute__((address_space(1))) void*)g,
        (__attribute__((address_space(3))) void*)l, 16, 0, 0);
}

// ---- 128x128 MFMA GEMM, m97 structure (3 blocks/CU!) + swapped MFMA + -----
// ---- vectorized XOR-swizzled LDS epilogue + bijective XCD swizzle.    -----
// A: M x K bf16 row-major, BT: N x K bf16. C = [relu](A@B + bias) bf16.
// 256 thr = 4 waves, wave tile 64x64. SWAPPED-operand MFMA:
// acc[i][j] reg r -> C[m0+wm+i*16+r16][n0+wn+j*16+u16*4+r]  (verified map)
// 48 KB LDS (As 8 + Bs 8 + eb 32) + ~164 unified regs -> 3 blocks/CU, so
// inter-block wave overlap (m114) covers the per-K-tile barrier drains.
template<bool RELU>
__global__ __launch_bounds__(256) void gemm128(
    const bf16_t* __restrict__ A, const bf16_t* __restrict__ BT,
    const float* __restrict__ bias, bf16_t* __restrict__ C,
    int N, int K, int nbx)
{
    __shared__ __align__(16) bf16_t As[128 * 32];   // [m][k] linear, 8 KB
    __shared__ __align__(16) bf16_t Bs[128 * 32];   // [n][k] linear, 8 KB
    __shared__ __align__(16) char   eb[32768];      // epilogue staging

    const int t    = threadIdx.x;
    const int lane = t & 63;
    const int w    = t >> 6;
    const int wm   = (w >> 1) << 6;
    const int wn   = (w & 1) << 6;

    // bijective XCD swizzle (nwg % 8 == 0 for our shapes)
    const int nwg = gridDim.x;
    int bid = blockIdx.x;
    int swz = ((nwg & 7) == 0) ? ((bid & 7) * (nwg >> 3) + (bid >> 3)) : bid;
    const int bx = swz % nbx, by = swz / nbx;
    const int m0 = by << 7, n0 = bx << 7;

    const int srow  = t >> 2;
    const int skoff = (t & 3) << 3;

    const bf16_t* Ap = A  + (size_t)(m0 + srow) * K + skoff;
    const bf16_t* Bp = BT + (size_t)(n0 + srow) * K + skoff;
    const size_t rstep = (size_t)64 * K;

    bf16_t* lA0 = As + ((w << 6)      ) * 8;
    bf16_t* lA1 = As + ((w << 6) + 256) * 8;
    bf16_t* lB0 = Bs + ((w << 6)      ) * 8;
    bf16_t* lB1 = Bs + ((w << 6) + 256) * 8;

    f32x4 acc[4][4];
#pragma unroll
    for (int i = 0; i < 4; ++i)
#pragma unroll
        for (int j = 0; j < 4; ++j) acc[i][j] = (f32x4){0.f, 0.f, 0.f, 0.f};

    const int r16  = lane & 15;
    const int u16  = lane >> 4;
    const int kblk = u16 << 3;

    for (int k0 = 0; k0 < K; k0 += 32) {
        __syncthreads();
        gload16(Ap + k0,         lA0);
        gload16(Ap + rstep + k0, lA1);
        gload16(Bp + k0,         lB0);
        gload16(Bp + rstep + k0, lB1);
        __syncthreads();

        bf16x8 af[4], bfr[4];
#pragma unroll
        for (int i = 0; i < 4; ++i) {
            af[i]  = *(const bf16x8*)&As[(wm + (i << 4) + r16) * 32 + kblk];
            bfr[i] = *(const bf16x8*)&Bs[(wn + (i << 4) + r16) * 32 + kblk];
        }
        // SWAPPED operands: D col <- B index path, row <- A row (r16)
#pragma unroll
        for (int i = 0; i < 4; ++i)
#pragma unroll
            for (int j = 0; j < 4; ++j)
                acc[i][j] = __builtin_amdgcn_mfma_f32_16x16x32_bf16(bfr[j], af[i], acc[i][j], 0, 0, 0);
    }

    __syncthreads();   // LDS reads all consumed (MFMA operand waits) -> reuse

    // ---- epilogue: bias+relu -> eb bf16[128][128], 16B-XOR swizzled ----
    // byte(row,col) = row*256 + ((col*2) ^ ((row&15)<<4))
    const int mBb = wm + r16;
    const int nBb = wn + (u16 << 2);
#pragma unroll
    for (int i = 0; i < 4; ++i) {
        const int row = mBb + (i << 4);
        const int xm  = (row & 15) << 4;
#pragma unroll
        for (int j = 0; j < 4; ++j) {
            const int nl = nBb + (j << 4);
            f32x4 bv = *(const f32x4*)(bias + n0 + nl);
            bf16x4 pk;
#pragma unroll
            for (int r = 0; r < 4; ++r) {
                float v = acc[i][j][r] + bv[r];
                if (RELU) v = fmaxf(v, 0.f);
                pk[r] = (bf16_t)v;
            }
            *(bf16x4*)(eb + row * 256 + ((nl << 1) ^ xm)) = pk;
        }
    }
    __syncthreads();
    // coalesced stores: 16 lanes x 16B = 256B contiguous per row
#pragma unroll
    for (int rp = 0; rp < 8; ++rp) {
        const int row = (rp << 4) + (t >> 4);
        const int c   = t & 15;
        bf16x8 v = *(const bf16x8*)(eb + row * 256 + ((c << 4) ^ ((row & 15) << 4)));
        *(bf16x8*)(C + (size_t)(m0 + row) * N + n0 + (c << 3)) = v;
    }
}

// ---- Control arm: r12's 256x256 4-phase gemm256 (unchanged), for layer 2 --
__device__ __forceinline__ void qmap(int q, int& row, int& u) {
    int prow = q >> 3;
    int v = (q & 7) ^ (prow & 7);
    row = (prow << 1) | (v >> 2);
    u = v & 3;
}
__device__ __forceinline__ int lds_elem(int row, int u) {
    int prow = row >> 1;
    int v = ((row & 1) << 2) | u;
    return prow * 64 + ((v ^ (prow & 7)) << 3);
}

template<bool RELU>
__global__ __launch_bounds__(512, 2) void gemm256(
    const bf16_t* __restrict__ A, const bf16_t* __restrict__ BT,
    const float* __restrict__ bias, bf16_t* __restrict__ C,
    int N, int K, int nbx)
{
    __shared__ bf16_t sm[2][2][2][8192];

    const int t    = threadIdx.x;
    const int lane = t & 63;
    const int w    = t >> 6;
    const int wr   = w >> 2;
    const int wc   = w & 3;
    const int r16  = lane & 15;
    const int u16  = lane >> 4;

    const int nwg = gridDim.x;
    int bid = blockIdx.x;
    int swz = ((nwg & 7) == 0) ? ((bid & 7) * (nwg >> 3) + (bid >> 3)) : bid;
    const int bx = swz % nbx, by = swz / nbx;
    const int m0 = by << 8, n0 = bx << 8;

    int r0, u0, r1, u1;
    qmap(t, r0, u0);
    qmap(t + 512, r1, u1);
    const bf16_t* gA0 = A  + (size_t)(m0 + r0) * K + (u0 << 3);
    const bf16_t* gA1 = A  + (size_t)(m0 + r1) * K + (u1 << 3);
    const bf16_t* gB0 = BT + (size_t)(n0 + r0) * K + (u0 << 3);
    const bf16_t* gB1 = BT + (size_t)(n0 + r1) * K + (u1 << 3);

    auto STAGE = [&](const bf16_t* g0, const bf16_t* g1, bf16_t* sl, int koff) {
        gload16(g0 + koff, sl + (w << 9));
        gload16(g1 + koff, sl + 4096 + (w << 9));
    };

    int aoff[8], boff[4];
#pragma unroll
    for (int i = 0; i < 8; ++i) aoff[i] = lds_elem((wr << 7) + (i << 4) + r16, u16);
#pragma unroll
    for (int j = 0; j < 4; ++j) boff[j] = lds_elem((wc << 6) + (j << 4) + r16, u16);

    f32x4 acc[8][4];
#pragma unroll
    for (int i = 0; i < 8; ++i)
#pragma unroll
        for (int j = 0; j < 4; ++j) acc[i][j] = (f32x4){0.f, 0.f, 0.f, 0.f};

    const int NT = K >> 6;

    STAGE(gA0, gA1, &sm[0][0][0][0], 0);
    STAGE(gB0, gB1, &sm[0][1][0][0], 0);
    STAGE(gA0, gA1, &sm[0][0][1][0], 32);
    STAGE(gB0, gB1, &sm[0][1][1][0], 32);
    STAGE(gA0, gA1, &sm[1][0][0][0], 64);
    STAGE(gB0, gB1, &sm[1][1][0][0], 64);
    asm volatile("s_waitcnt vmcnt(8)" ::: "memory");
    __builtin_amdgcn_s_barrier();

    bf16x8 af0[4], af1[4], bfr[4];
#pragma unroll
    for (int i = 0; i < 4; ++i) af0[i] = *(const bf16x8*)(&sm[0][0][0][0] + aoff[i]);

    for (int kt = 0; kt < NT; ++kt) {
        const int c  = kt & 1;
        const int c1 = c ^ 1;
        const bool s12 = (kt + 1) < NT;
        const bool s34 = (kt + 2) < NT;
        const int k12 = ((kt + 1) << 6) + 32;
        const int k34 = (kt + 2) << 6;
        const bf16_t* sA1 = &sm[c][0][1][0];
        const bf16_t* sB0 = &sm[c][1][0][0];
        const bf16_t* sB1 = &sm[c][1][1][0];

        // phase 1
#pragma unroll
        for (int j = 0; j < 4; ++j) bfr[j] = *(const bf16x8*)(sB0 + boff[j]);
#pragma unroll
        for (int i = 0; i < 4; ++i) af1[i] = *(const bf16x8*)(&sm[c][0][0][0] + aoff[4 + i]);
        if (s12) STAGE(gA0, gA1, &sm[c1][0][1][0], k12);
        __builtin_amdgcn_s_barrier();
        __builtin_amdgcn_s_setprio(1);
#pragma unroll
        for (int i = 0; i < 4; ++i)
#pragma unroll
            for (int j = 0; j < 4; ++j)
                acc[i][j] = __builtin_amdgcn_mfma_f32_16x16x32_bf16(bfr[j], af0[i], acc[i][j], 0, 0, 0);
        __builtin_amdgcn_s_setprio(0);
        __builtin_amdgcn_s_barrier();

        // phase 2
        if (s12) STAGE(gB0, gB1, &sm[c1][1][1][0], k12);
        if (s12) asm volatile("s_waitcnt vmcnt(8)" ::: "memory");
        else     asm volatile("s_waitcnt vmcnt(0)" ::: "memory");
        __builtin_amdgcn_s_barrier();
#pragma unroll
        for (int i = 0; i < 4; ++i) af0[i] = *(const bf16x8*)(sA1 + aoff[i]);
        __builtin_amdgcn_s_setprio(1);
#pragma unroll
        for (int i = 0; i < 4; ++i)
#pragma unroll
            for (int j = 0; j < 4; ++j)
                acc[4 + i][j] = __builtin_amdgcn_mfma_f32_16x16x32_bf16(bfr[j], af1[i], acc[4 + i][j], 0, 0, 0);
        __builtin_amdgcn_s_setprio(0);
        __builtin_amdgcn_s_barrier();

        // phase 3
#pragma unroll
        for (int j = 0; j < 4; ++j) bfr[j] = *(const bf16x8*)(sB1 + boff[j]);
#pragma unroll
        for (int i = 0; i < 4; ++i) af1[i] = *(const bf16x8*)(sA1 + aoff[4 + i]);
        if (s34) STAGE(gA0, gA1, &sm[c][0][0][0], k34);
        __builtin_amdgcn_s_barrier();
        __builtin_amdgcn_s_setprio(1);
#pragma unroll
        for (int i = 0; i < 4; ++i)
#pragma unroll
            for (int j = 0; j < 4; ++j)
                acc[i][j] = __builtin_amdgcn_mfma_f32_16x16x32_bf16(bfr[j], af0[i], acc[i][j], 0, 0, 0);
        __builtin_amdgcn_s_setprio(0);
        __builtin_amdgcn_s_barrier();

        // phase 4
        if (s34) STAGE(gB0, gB1, &sm[c][1][0][0], k34);
        if (s34)      asm volatile("s_waitcnt vmcnt(8)" ::: "memory");
        else if (s12) asm volatile("s_waitcnt vmcnt(4)" ::: "memory");
        __builtin_amdgcn_s_barrier();
        if (s12) {
#pragma unroll
            for (int i = 0; i < 4; ++i)
                af0[i] = *(const bf16x8*)(&sm[c1][0][0][0] + aoff[i]);
        }
        __builtin_amdgcn_s_setprio(1);
#pragma unroll
        for (int i = 0; i < 4; ++i)
#pragma unroll
            for (int j = 0; j < 4; ++j)
                acc[4 + i][j] = __builtin_amdgcn_mfma_f32_16x16x32_bf16(bfr[j], af1[i], acc[4 + i][j], 0, 0, 0);
        __builtin_amdgcn_s_setprio(0);
        __builtin_amdgcn_s_barrier();
    }

    __syncthreads();

    char* eb = (char*)&sm[0][0][0][0];
    const int mBb = (wr << 7) + r16;
    const int nBb = (wc << 6) + (u16 << 2);
#pragma unroll
    for (int i = 0; i < 8; ++i) {
        const int m = mBb + (i << 4);
        const int xm = (m & 15) << 4;
#pragma unroll
        for (int j = 0; j < 4; ++j) {
            const int nl = nBb + (j << 4);
            f32x4 bv = *(const f32x4*)(bias + n0 + nl);
            bf16x4 pk;
#pragma unroll
            for (int r = 0; r < 4; ++r) {
                float v = acc[i][j][r] + bv[r];
                if (RELU) v = fmaxf(v, 0.f);
                pk[r] = (bf16_t)v;
            }
            *(bf16x4*)(eb + m * 512 + ((nl << 1) ^ xm)) = pk;
        }
    }
    __syncthreads();
    const int cc = t & 31;
    const int rr = t >> 5;
#pragma unroll
    for (int rp = 0; rp < 16; ++rp) {
        const int m = (rp << 4) + rr;
        bf16x8 v = *(const bf16x8*)(eb + m * 512 + (((cc << 4) ^ ((m & 15) << 4)) & 511));
        *(bf16x8*)(C + (size_t)(m0 + m) * N + n0 + (cc << 3)) = v;
    }
}

// ---- fused head: hd = h2 @ Whead + bhead, probs + loss partial ------------
__global__ __launch_bounds__(256) void head_fused(
    const bf16_t* __restrict__ A, const bf16_t* __restrict__ BT,
    const float* __restrict__ bias, const int* __restrict__ data,
    float* __restrict__ probs_out, float* __restrict__ partials,
    int K, int row0)
{
    __shared__ __align__(16) bf16_t As[128 * 32];
    __shared__ __align__(16) bf16_t Bs[128 * 32];
    __shared__ float hdl[128 * 128];

    const int t    = threadIdx.x;
    const int lane = t & 63;
    const int w    = t >> 6;
    const int wm   = (w >> 1) << 6;
    const int wn   = (w & 1) << 6;
    const int m0l  = blockIdx.x << 7;

    const int srow  = t >> 2;
    const int skoff = (t & 3) << 3;

    const bf16_t* Ap = A  + (size_t)(m0l + srow) * K + skoff;
    const bf16_t* Bp = BT + (size_t)srow * K + skoff;
    const size_t rstep = (size_t)64 * K;

    bf16_t* lA0 = As + ((w << 6)      ) * 8;
    bf16_t* lA1 = As + ((w << 6) + 256) * 8;
    bf16_t* lB0 = Bs + ((w << 6)      ) * 8;
    bf16_t* lB1 = Bs + ((w << 6) + 256) * 8;

    f32x4 acc[4][4];
#pragma unroll
    for (int i = 0; i < 4; ++i)
#pragma unroll
        for (int j = 0; j < 4; ++j) acc[i][j] = (f32x4){0.f, 0.f, 0.f, 0.f};

    const int r16  = lane & 15;
    const int u16  = lane >> 4;
    const int kblk = u16 << 3;

    for (int k0 = 0; k0 < K; k0 += 32) {
        __syncthreads();
        gload16(Ap + k0,         lA0);
        gload16(Ap + rstep + k0, lA1);
        gload16(Bp + k0,         lB0);
        gload16(Bp + rstep + k0, lB1);
        __syncthreads();

        bf16x8 af[4], bfr[4];
#pragma unroll
        for (int i = 0; i < 4; ++i) {
            af[i]  = *(const bf16x8*)&As[(wm + (i << 4) + r16) * 32 + kblk];
            bfr[i] = *(const bf16x8*)&Bs[(wn + (i << 4) + r16) * 32 + kblk];
        }
#pragma unroll
        for (int i = 0; i < 4; ++i)
#pragma unroll
            for (int j = 0; j < 4; ++j)
                acc[i][j] = __builtin_amdgcn_mfma_f32_16x16x32_bf16(af[i], bfr[j], acc[i][j], 0, 0, 0);
    }

#pragma unroll
    for (int j = 0; j < 4; ++j) {
        const int col = wn + (j << 4) + r16;
        const float bv = bias[col];
#pragma unroll
        for (int i = 0; i < 4; ++i) {
            const int rb = wm + (i << 4) + (u16 << 2);
#pragma unroll
            for (int r = 0; r < 4; ++r)
                hdl[(rb + r) * 128 + col] = acc[i][j][r] + bv;
        }
    }
    __syncthreads();

    float lsum = 0.f;
    const int item = t & 15;
    const int cp   = 4 + (item & 3);
#pragma unroll
    for (int p = 0; p < 8; ++p) {
        const int row = (p << 4) + (t >> 4);
        const float* h = hdl + row * 128;
        const size_t grow = (size_t)row0 + m0l + row;

        const float f = h[item];
        float cumP[7];
        float cum = 0.f;
#pragma unroll
        for (int c = 0; c < 7; ++c) {
            if (c < cp) {
                float e = fmaxf(expf(h[16 + item * 7 + c]), EPSV);
                cum += e;
                float s = 1.f / (1.f + expf(f - cum));
                cumP[c] = fminf(fmaxf(s, EPSV), 1.f - EPSV);
            } else {
                cumP[c] = 0.f;
            }
        }
        float probs[8];
#pragma unroll
        for (int k = 0; k < 8; ++k) {
            float v;
            if (k < cp)       v = (k == 0) ? cumP[0] : (cumP[k] - cumP[k - 1]);
            else if (k == cp) v = 1.f - cumP[cp - 1];
            else              v = 1.f;
            probs[k] = fminf(fmaxf(v, EPSV), 1.f - EPSV);
        }
        float* dst = probs_out + (grow * 16 + item) * 8;
#pragma unroll
        for (int k = 0; k < 8; ++k) dst[k] = probs[k];

        const int d = data[grow * 16 + item];
        float g = probs[0];
#pragma unroll
        for (int k = 1; k < 8; ++k) g = (d == k) ? probs[k] : g;
        lsum += -logf(g);
    }

    __syncthreads();
    float* red = (float*)As;
    red[t] = lsum;
    __syncthreads();
#pragma unroll
    for (int s2 = 128; s2 > 0; s2 >>= 1) {
        if (t < s2) red[t] += red[t + s2];
        __syncthreads();
    }
    if (t == 0) partials[(row0 >> 7) + blockIdx.x] = red[0];
}

// ---------------- fp32 -> bf16 conversion (8 elems/thread) ----------------
__global__ __launch_bounds__(256) void convert_x(
    const float* __restrict__ in, bf16_t* __restrict__ out, int n8)
{
    int i = blockIdx.x * 256 + threadIdx.x;
    if (i >= n8) return;
    const float4* p = (const float4*)in;
    float4 a = p[2 * i], b = p[2 * i + 1];
    bf16x8 v;
    v[0] = (bf16_t)a.x; v[1] = (bf16_t)a.y; v[2] = (bf16_t)a.z; v[3] = (bf16_t)a.w;
    v[4] = (bf16_t)b.x; v[5] = (bf16_t)b.y; v[6] = (bf16_t)b.z; v[7] = (bf16_t)b.w;
    ((bf16x8*)out)[i] = v;
}

// ---------------- transpose weight K x N fp32 -> N x K bf16 ----------------
__global__ __launch_bounds__(256) void transpose_w(
    const float* __restrict__ in, bf16_t* __restrict__ out,
    int kshift, int N, int total)
{
    int idx = blockIdx.x * 256 + threadIdx.x;
    if (idx >= total) return;
    int n = idx >> kshift;
    int k = idx & ((1 << kshift) - 1);
    out[idx] = (bf16_t)in[(size_t)k * N + n];
}

// ---------------- pack head: WheadT (128 x 512) bf16 + bhead (128) f32 -----
__global__ __launch_bounds__(256) void pack_head(
    const float* __restrict__ Wf, const float* __restrict__ bfv,
    const float* __restrict__ Wk, const float* __restrict__ bk,
    bf16_t* __restrict__ WhT, float* __restrict__ bhead)
{
    int idx = blockIdx.x * 256 + threadIdx.x;
    int n = idx >> 9;
    int k = idx & 511;
    float v;
    if (n < 16) {
        v = Wf[k * 16 + n];
    } else {
        int m = n - 16;
        int i = m / 7, c = m % 7;
        v = Wk[(size_t)i * 3584 + (size_t)k * 7 + c];
    }
    WhT[idx] = (bf16_t)v;
    if (idx < 128) bhead[idx] = (idx < 16) ? bfv[idx] : bk[idx - 16];
}

__global__ __launch_bounds__(256) void reduce_loss(
    const float* __restrict__ partials, int n, float* __restrict__ out, float scale)
{
    __shared__ float red[256];
    float s = 0.f;
    for (int i = threadIdx.x; i < n; i += 256) s += partials[i];
    red[threadIdx.x] = s;
    __syncthreads();
    for (int k = 128; k > 0; k >>= 1) {
        if (threadIdx.x < k) red[threadIdx.x] += red[threadIdx.x + k];
        __syncthreads();
    }
    if (threadIdx.x == 0) out[0] = red[0] * scale;
}

extern "C" void kernel_launch(void* const* d_in, const int* in_sizes, int n_in,
                              void* d_out, int out_size, void* d_ws, size_t ws_size,
                              hipStream_t stream)
{
    const float* x   = (const float*)d_in[0];
    const int*   dat = (const int*)d_in[1];
    const float* W1  = (const float*)d_in[2];
    const float* b1  = (const float*)d_in[3];
    const float* W2  = (const float*)d_in[4];
    const float* b2  = (const float*)d_in[5];
    const float* Wf  = (const float*)d_in[6];
    const float* bfv = (const float*)d_in[7];
    const float* Wk  = (const float*)d_in[8];
    const float* bk  = (const float*)d_in[9];
    float* out = (float*)d_out;

    const int B = 65536, DIN = 512, H1 = 1024, H2 = 512;

    char* cur = (char*)d_ws;
    auto carve = [&](size_t bytes) {
        char* p = cur;
        cur += (bytes + 255) & ~(size_t)255;
        return p;
    };
    float*  partials = (float*)carve(4096 * 4);
    float*  bhead    = (float*)carve(512);
    bf16_t* W1T      = (bf16_t*)carve((size_t)H1 * DIN * 2);
    bf16_t* W2T      = (bf16_t*)carve((size_t)H2 * H1 * 2);
    bf16_t* WhT      = (bf16_t*)carve((size_t)128 * H2 * 2);

    // per-row slice bytes: xb 1024 + h1 2048 + h2 1024 = 4096
    size_t used = (size_t)(cur - (char*)d_ws);
    size_t avail = (ws_size > used + 1024) ? (ws_size - used - 1024) : 0;
    int SLICE = 2048;
    const int cands[6] = {65536, 32768, 16384, 8192, 4096, 2048};
    for (int ci = 0; ci < 6; ++ci) {
        if ((size_t)cands[ci] * 4096 <= avail) { SLICE = cands[ci]; break; }
    }
    bf16_t* xb = (bf16_t*)carve((size_t)SLICE * DIN * 2);
    bf16_t* h1 = (bf16_t*)carve((size_t)SLICE * H1 * 2);
    bf16_t* h2 = (bf16_t*)carve((size_t)SLICE * H2 * 2);

    transpose_w<<<(H1 * DIN + 255) / 256, 256, 0, stream>>>(W1, W1T, 9,  H1, H1 * DIN);
    transpose_w<<<(H2 * H1 + 255) / 256, 256, 0, stream>>>(W2, W2T, 10, H2, H2 * H1);
    pack_head<<<256, 256, 0, stream>>>(Wf, bfv, Wk, bk, WhT, bhead);

    for (int r0 = 0; r0 < B; r0 += SLICE) {
        convert_x<<<SLICE / 4, 256, 0, stream>>>(x + (size_t)r0 * DIN, xb, SLICE * DIN / 8);
        // A/B: layer 1 = gemm128 (3 blocks/CU, m97 structure)
        gemm128<true><<<(SLICE / 128) * (H1 / 128), 256, 0, stream>>>(xb, W1T, b1, h1, H1, DIN, H1 / 128);
        // control: layer 2 = gemm256 (r12, unchanged)
        gemm256<true><<<(SLICE / 256) * (H2 / 256), 512, 0, stream>>>(h1, W2T, b2, h2, H2, H1, H2 / 256);
        head_fused<<<SLICE / 128, 256, 0, stream>>>(h2, WhT, bhead, dat, out + 1, partials, H2, r0);
    }
    reduce_loss<<<1, 256, 0, stream>>>(partials, B / 128, out, 1.0f / B);
}

// Round 14
// 234.683 us; speedup vs baseline: 1.2026x; 1.2026x over previous
//
#include <hip/hip_runtime.h>
#include <cmath>

#define EPSV 1e-8f

typedef __bf16 bf16_t;
typedef __bf16 bf16x8 __attribute__((ext_vector_type(8)));
typedef __bf16 bf16x4 __attribute__((ext_vector_type(4)));
typedef float f32x4 __attribute__((ext_vector_type(4)));

__device__ __forceinline__ void gload16(const void* g, void* l) {
    __builtin_amdgcn_global_load_lds(
        (const __attribute__((address_space(1))) void*)g,
        (__attribute__((address_space(3))) void*)l, 16, 0, 0);
}

// Swizzled LDS half-tile: 256 rows x 32 k (bf16), 16 KB = 1024 16B-units.
__device__ __forceinline__ void qmap(int q, int& row, int& u) {
    int prow = q >> 3;
    int v = (q & 7) ^ (prow & 7);
    row = (prow << 1) | (v >> 2);
    u = v & 3;
}
__device__ __forceinline__ int lds_elem(int row, int u) {
    int prow = row >> 1;
    int v = ((row & 1) << 2) | u;
    return prow * 64 + ((v ^ (prow & 7)) << 3);   // bf16-element offset
}

// ==== gemm256f: 256x256 4-phase GEMM with FUSED fp32->bf16 A conversion ====
// A: M x K FP32 row-major (x itself). BT: N x K bf16. C = relu(A@B+bias) bf16.
// B staging: global_load_lds (unchanged). A staging: global fp32 -> regs ->
// cvt -> ds_write_b128 into the SAME qmap LDS image the loop already reads.
// Mixed vmcnt FIFO per K-tile: ph1 issues 4 fp32 A1(t+1); ph2 issues 2 glds
// B1(t+1), vmcnt(8) retires A0(t+1):4 -> cvt+write A0(t+1) after MFMA;
// ph3 issues 4 fp32 A0(t+2); ph4 issues 2 glds B0(t+2), vmcnt(8) retires
// B0(t+1):2 + A1(t+1):4 -> cvt+write A1(t+1) after MFMA. Writer lgkmcnt(0)
// before ph2/ph4 closing barriers gives cross-wave visibility (readers are
// >=1 barrier later). Tails: ph2 vmcnt(0) when last tile; ph4 vmcnt(2) when
// kt+2==NT (retires B0+A1, leaves B1:2). Prologue issues A0(1) BEFORE B0(1)
// so kt=0's ph2 vmcnt(8) retires exactly A0(1) (steady-state FIFO order).
template<bool RELU>
__global__ __launch_bounds__(512, 2) void gemm256f(
    const float* __restrict__ A, const bf16_t* __restrict__ BT,
    const float* __restrict__ bias, bf16_t* __restrict__ C,
    int N, int K, int nbx)
{
    __shared__ bf16_t sm[2][2][2][8192];   // [buf][A/B][kslice][16KB] = 128 KB

    const int t    = threadIdx.x;
    const int lane = t & 63;
    const int w    = t >> 6;
    const int wr   = w >> 2;
    const int wc   = w & 3;
    const int r16  = lane & 15;
    const int u16  = lane >> 4;

    const int nwg = gridDim.x;
    int bid = blockIdx.x;
    int swz = ((nwg & 7) == 0) ? ((bid & 7) * (nwg >> 3) + (bid >> 3)) : bid;
    const int bx = swz % nbx, by = swz / nbx;
    const int m0 = by << 8, n0 = bx << 8;

    int r0, u0, r1, u1;
    qmap(t, r0, u0);
    qmap(t + 512, r1, u1);
    const float*  gA0 = A  + (size_t)(m0 + r0) * K + (u0 << 3);
    const float*  gA1 = A  + (size_t)(m0 + r1) * K + (u1 << 3);
    const bf16_t* gB0 = BT + (size_t)(n0 + r0) * K + (u0 << 3);
    const bf16_t* gB1 = BT + (size_t)(n0 + r1) * K + (u1 << 3);

    auto STAGE_B = [&](bf16_t* sl, int koff) {
        gload16(gB0 + koff, sl + (w << 9));
        gload16(gB1 + koff, sl + 4096 + (w << 9));
    };

    f32x4 ar[2][4];   // two in-flight A k-slices (slot 0/1), 2 units x 32B
    auto LOAD_A = [&](int slot, int koff) {
        ar[slot][0] = *(const f32x4*)(gA0 + koff);
        ar[slot][1] = *(const f32x4*)(gA0 + koff + 4);
        ar[slot][2] = *(const f32x4*)(gA1 + koff);
        ar[slot][3] = *(const f32x4*)(gA1 + koff + 4);
    };
    // write units p=t (from ar[.][0..1]) and p=t+512 (from ar[.][2..3]);
    // unit p lands at element p*8 -- identical image to global_load_lds.
    auto WRITE_A = [&](int slot, bf16_t* sl) {
        bf16x8 v0, v1;
#pragma unroll
        for (int e = 0; e < 4; ++e) {
            v0[e]     = (bf16_t)ar[slot][0][e];
            v0[4 + e] = (bf16_t)ar[slot][1][e];
            v1[e]     = (bf16_t)ar[slot][2][e];
            v1[4 + e] = (bf16_t)ar[slot][3][e];
        }
        *(bf16x8*)(sl + ((size_t)t << 3))         = v0;
        *(bf16x8*)(sl + ((size_t)(t + 512) << 3)) = v1;
    };

    int aoff[8], boff[4];
#pragma unroll
    for (int i = 0; i < 8; ++i) aoff[i] = lds_elem((wr << 7) + (i << 4) + r16, u16);
#pragma unroll
    for (int j = 0; j < 4; ++j) boff[j] = lds_elem((wc << 6) + (j << 4) + r16, u16);

    f32x4 acc[8][4];
#pragma unroll
    for (int i = 0; i < 8; ++i)
#pragma unroll
        for (int j = 0; j < 4; ++j) acc[i][j] = (f32x4){0.f, 0.f, 0.f, 0.f};

    const int NT = K >> 6;   // NT >= 8 for our shapes

    // ---- prologue ----
    LOAD_A(0, 0);                         // A0(0): 4
    LOAD_A(1, 32);                        // A1(0): 4
    STAGE_B(&sm[0][1][0][0], 0);          // B0(0): 2
    STAGE_B(&sm[0][1][1][0], 32);         // B1(0): 2
    asm volatile("s_waitcnt vmcnt(4)" ::: "memory");   // A0(0),A1(0) retired
    WRITE_A(0, &sm[0][0][0][0]);
    WRITE_A(1, &sm[0][0][1][0]);
    LOAD_A(0, 64);                        // A0(1): 4  (BEFORE B0(1)!)
    STAGE_B(&sm[1][1][0][0], 64);         // B0(1): 2
    asm volatile("s_waitcnt vmcnt(6)" ::: "memory");   // B0(0),B1(0) in LDS
    asm volatile("s_waitcnt lgkmcnt(0)" ::: "memory"); // A writes visible
    __builtin_amdgcn_s_barrier();

    bf16x8 af0[4], af1[4], bfr[4];
#pragma unroll
    for (int i = 0; i < 4; ++i) af0[i] = *(const bf16x8*)(&sm[0][0][0][0] + aoff[i]);

    for (int kt = 0; kt < NT; ++kt) {
        const int c  = kt & 1;
        const int c1 = c ^ 1;
        const bool s12 = (kt + 1) < NT;
        const bool s34 = (kt + 2) < NT;
        const int k12 = ((kt + 1) << 6) + 32;
        const int k34 = (kt + 2) << 6;
        const bf16_t* sA0 = &sm[c][0][0][0];
        const bf16_t* sA1 = &sm[c][0][1][0];
        const bf16_t* sB0 = &sm[c][1][0][0];
        const bf16_t* sB1 = &sm[c][1][1][0];

        // ---- phase 1: MFMA(B0, A0[0:4]) ----
#pragma unroll
        for (int j = 0; j < 4; ++j) bfr[j] = *(const bf16x8*)(sB0 + boff[j]);
#pragma unroll
        for (int i = 0; i < 4; ++i) af1[i] = *(const bf16x8*)(sA0 + aoff[4 + i]);
        if (s12) LOAD_A(1, k12);                       // A1(t+1) -> regs
        __builtin_amdgcn_s_barrier();
        __builtin_amdgcn_s_setprio(1);
#pragma unroll
        for (int i = 0; i < 4; ++i)
#pragma unroll
            for (int j = 0; j < 4; ++j)
                acc[i][j] = __builtin_amdgcn_mfma_f32_16x16x32_bf16(bfr[j], af0[i], acc[i][j], 0, 0, 0);
        __builtin_amdgcn_s_setprio(0);
        __builtin_amdgcn_s_barrier();

        // ---- phase 2: MFMA(B0, A0[4:8]); write A0(t+1) ----
        if (s12) STAGE_B(&sm[c1][1][1][0], k12);       // B1(t+1)
        if (s12) asm volatile("s_waitcnt vmcnt(8)" ::: "memory");  // A0(t+1) regs ok
        else     asm volatile("s_waitcnt vmcnt(0)" ::: "memory");
        __builtin_amdgcn_s_barrier();
#pragma unroll
        for (int i = 0; i < 4; ++i) af0[i] = *(const bf16x8*)(sA1 + aoff[i]);
        __builtin_amdgcn_s_setprio(1);
#pragma unroll
        for (int i = 0; i < 4; ++i)
#pragma unroll
            for (int j = 0; j < 4; ++j)
                acc[4 + i][j] = __builtin_amdgcn_mfma_f32_16x16x32_bf16(bfr[j], af1[i], acc[4 + i][j], 0, 0, 0);
        __builtin_amdgcn_s_setprio(0);
        if (s12) {
            WRITE_A(0, &sm[c1][0][0][0]);              // A0(t+1) -> LDS
            asm volatile("s_waitcnt lgkmcnt(0)" ::: "memory");
        }
        __builtin_amdgcn_s_barrier();

        // ---- phase 3: MFMA(B1, A1[0:4]) ----
#pragma unroll
        for (int j = 0; j < 4; ++j) bfr[j] = *(const bf16x8*)(sB1 + boff[j]);
#pragma unroll
        for (int i = 0; i < 4; ++i) af1[i] = *(const bf16x8*)(sA1 + aoff[4 + i]);
        if (s34) LOAD_A(0, k34);                       // A0(t+2) -> regs
        __builtin_amdgcn_s_barrier();
        __builtin_amdgcn_s_setprio(1);
#pragma unroll
        for (int i = 0; i < 4; ++i)
#pragma unroll
            for (int j = 0; j < 4; ++j)
                acc[i][j] = __builtin_amdgcn_mfma_f32_16x16x32_bf16(bfr[j], af0[i], acc[i][j], 0, 0, 0);
        __builtin_amdgcn_s_setprio(0);
        __builtin_amdgcn_s_barrier();

        // ---- phase 4: MFMA(B1, A1[4:8]); write A1(t+1) ----
        if (s34) STAGE_B(&sm[c][1][0][0], k34);        // B0(t+2) over consumed
        if (s34)      asm volatile("s_waitcnt vmcnt(8)" ::: "memory");  // B0(t+1)+A1(t+1)
        else if (s12) asm volatile("s_waitcnt vmcnt(2)" ::: "memory");  // same, tail
        __builtin_amdgcn_s_barrier();
        if (s12) {
#pragma unroll
            for (int i = 0; i < 4; ++i)
                af0[i] = *(const bf16x8*)(&sm[c1][0][0][0] + aoff[i]);  // A0(t+1)
        }
        __builtin_amdgcn_s_setprio(1);
#pragma unroll
        for (int i = 0; i < 4; ++i)
#pragma unroll
            for (int j = 0; j < 4; ++j)
                acc[4 + i][j] = __builtin_amdgcn_mfma_f32_16x16x32_bf16(bfr[j], af1[i], acc[4 + i][j], 0, 0, 0);
        __builtin_amdgcn_s_setprio(0);
        if (s12) {
            WRITE_A(1, &sm[c1][0][1][0]);              // A1(t+1) -> LDS
            asm volatile("s_waitcnt lgkmcnt(0)" ::: "memory");
        }
        __builtin_amdgcn_s_barrier();
    }

    __syncthreads();

    // epilogue: bias+relu, LDS-staged, coalesced bf16x8 stores
    char* eb = (char*)&sm[0][0][0][0];
    const int mBb = (wr << 7) + r16;
    const int nBb = (wc << 6) + (u16 << 2);
#pragma unroll
    for (int i = 0; i < 8; ++i) {
        const int m = mBb + (i << 4);
        const int xm = (m & 15) << 4;
#pragma unroll
        for (int j = 0; j < 4; ++j) {
            const int nl = nBb + (j << 4);
            f32x4 bv = *(const f32x4*)(bias + n0 + nl);
            bf16x4 pk;
#pragma unroll
            for (int r = 0; r < 4; ++r) {
                float v = acc[i][j][r] + bv[r];
                if (RELU) v = fmaxf(v, 0.f);
                pk[r] = (bf16_t)v;
            }
            *(bf16x4*)(eb + m * 512 + ((nl << 1) ^ xm)) = pk;
        }
    }
    __syncthreads();
    const int cc = t & 31;
    const int rr = t >> 5;
#pragma unroll
    for (int rp = 0; rp < 16; ++rp) {
        const int m = (rp << 4) + rr;
        bf16x8 v = *(const bf16x8*)(eb + m * 512 + (((cc << 4) ^ ((m & 15) << 4)) & 511));
        *(bf16x8*)(C + (size_t)(m0 + m) * N + n0 + (cc << 3)) = v;
    }
}

// ==== gemm256: r12's proven bf16-input 4-phase kernel (layer 2) ====
template<bool RELU>
__global__ __launch_bounds__(512, 2) void gemm256(
    const bf16_t* __restrict__ A, const bf16_t* __restrict__ BT,
    const float* __restrict__ bias, bf16_t* __restrict__ C,
    int N, int K, int nbx)
{
    __shared__ bf16_t sm[2][2][2][8192];

    const int t    = threadIdx.x;
    const int lane = t & 63;
    const int w    = t >> 6;
    const int wr   = w >> 2;
    const int wc   = w & 3;
    const int r16  = lane & 15;
    const int u16  = lane >> 4;

    const int nwg = gridDim.x;
    int bid = blockIdx.x;
    int swz = ((nwg & 7) == 0) ? ((bid & 7) * (nwg >> 3) + (bid >> 3)) : bid;
    const int bx = swz % nbx, by = swz / nbx;
    const int m0 = by << 8, n0 = bx << 8;

    int r0, u0, r1, u1;
    qmap(t, r0, u0);
    qmap(t + 512, r1, u1);
    const bf16_t* gA0 = A  + (size_t)(m0 + r0) * K + (u0 << 3);
    const bf16_t* gA1 = A  + (size_t)(m0 + r1) * K + (u1 << 3);
    const bf16_t* gB0 = BT + (size_t)(n0 + r0) * K + (u0 << 3);
    const bf16_t* gB1 = BT + (size_t)(n0 + r1) * K + (u1 << 3);

    auto STAGE = [&](const bf16_t* g0, const bf16_t* g1, bf16_t* sl, int koff) {
        gload16(g0 + koff, sl + (w << 9));
        gload16(g1 + koff, sl + 4096 + (w << 9));
    };

    int aoff[8], boff[4];
#pragma unroll
    for (int i = 0; i < 8; ++i) aoff[i] = lds_elem((wr << 7) + (i << 4) + r16, u16);
#pragma unroll
    for (int j = 0; j < 4; ++j) boff[j] = lds_elem((wc << 6) + (j << 4) + r16, u16);

    f32x4 acc[8][4];
#pragma unroll
    for (int i = 0; i < 8; ++i)
#pragma unroll
        for (int j = 0; j < 4; ++j) acc[i][j] = (f32x4){0.f, 0.f, 0.f, 0.f};

    const int NT = K >> 6;

    STAGE(gA0, gA1, &sm[0][0][0][0], 0);
    STAGE(gB0, gB1, &sm[0][1][0][0], 0);
    STAGE(gA0, gA1, &sm[0][0][1][0], 32);
    STAGE(gB0, gB1, &sm[0][1][1][0], 32);
    STAGE(gA0, gA1, &sm[1][0][0][0], 64);
    STAGE(gB0, gB1, &sm[1][1][0][0], 64);
    asm volatile("s_waitcnt vmcnt(8)" ::: "memory");
    __builtin_amdgcn_s_barrier();

    bf16x8 af0[4], af1[4], bfr[4];
#pragma unroll
    for (int i = 0; i < 4; ++i) af0[i] = *(const bf16x8*)(&sm[0][0][0][0] + aoff[i]);

    for (int kt = 0; kt < NT; ++kt) {
        const int c  = kt & 1;
        const int c1 = c ^ 1;
        const bool s12 = (kt + 1) < NT;
        const bool s34 = (kt + 2) < NT;
        const int k12 = ((kt + 1) << 6) + 32;
        const int k34 = (kt + 2) << 6;
        const bf16_t* sA1 = &sm[c][0][1][0];
        const bf16_t* sB0 = &sm[c][1][0][0];
        const bf16_t* sB1 = &sm[c][1][1][0];

        // phase 1
#pragma unroll
        for (int j = 0; j < 4; ++j) bfr[j] = *(const bf16x8*)(sB0 + boff[j]);
#pragma unroll
        for (int i = 0; i < 4; ++i) af1[i] = *(const bf16x8*)(&sm[c][0][0][0] + aoff[4 + i]);
        if (s12) STAGE(gA0, gA1, &sm[c1][0][1][0], k12);
        __builtin_amdgcn_s_barrier();
        __builtin_amdgcn_s_setprio(1);
#pragma unroll
        for (int i = 0; i < 4; ++i)
#pragma unroll
            for (int j = 0; j < 4; ++j)
                acc[i][j] = __builtin_amdgcn_mfma_f32_16x16x32_bf16(bfr[j], af0[i], acc[i][j], 0, 0, 0);
        __builtin_amdgcn_s_setprio(0);
        __builtin_amdgcn_s_barrier();

        // phase 2
        if (s12) STAGE(gB0, gB1, &sm[c1][1][1][0], k12);
        if (s12) asm volatile("s_waitcnt vmcnt(8)" ::: "memory");
        else     asm volatile("s_waitcnt vmcnt(0)" ::: "memory");
        __builtin_amdgcn_s_barrier();
#pragma unroll
        for (int i = 0; i < 4; ++i) af0[i] = *(const bf16x8*)(sA1 + aoff[i]);
        __builtin_amdgcn_s_setprio(1);
#pragma unroll
        for (int i = 0; i < 4; ++i)
#pragma unroll
            for (int j = 0; j < 4; ++j)
                acc[4 + i][j] = __builtin_amdgcn_mfma_f32_16x16x32_bf16(bfr[j], af1[i], acc[4 + i][j], 0, 0, 0);
        __builtin_amdgcn_s_setprio(0);
        __builtin_amdgcn_s_barrier();

        // phase 3
#pragma unroll
        for (int j = 0; j < 4; ++j) bfr[j] = *(const bf16x8*)(sB1 + boff[j]);
#pragma unroll
        for (int i = 0; i < 4; ++i) af1[i] = *(const bf16x8*)(sA1 + aoff[4 + i]);
        if (s34) STAGE(gA0, gA1, &sm[c][0][0][0], k34);
        __builtin_amdgcn_s_barrier();
        __builtin_amdgcn_s_setprio(1);
#pragma unroll
        for (int i = 0; i < 4; ++i)
#pragma unroll
            for (int j = 0; j < 4; ++j)
                acc[i][j] = __builtin_amdgcn_mfma_f32_16x16x32_bf16(bfr[j], af0[i], acc[i][j], 0, 0, 0);
        __builtin_amdgcn_s_setprio(0);
        __builtin_amdgcn_s_barrier();

        // phase 4
        if (s34) STAGE(gB0, gB1, &sm[c][1][0][0], k34);
        if (s34)      asm volatile("s_waitcnt vmcnt(8)" ::: "memory");
        else if (s12) asm volatile("s_waitcnt vmcnt(4)" ::: "memory");
        __builtin_amdgcn_s_barrier();
        if (s12) {
#pragma unroll
            for (int i = 0; i < 4; ++i)
                af0[i] = *(const bf16x8*)(&sm[c1][0][0][0] + aoff[i]);
        }
        __builtin_amdgcn_s_setprio(1);
#pragma unroll
        for (int i = 0; i < 4; ++i)
#pragma unroll
            for (int j = 0; j < 4; ++j)
                acc[4 + i][j] = __builtin_amdgcn_mfma_f32_16x16x32_bf16(bfr[j], af1[i], acc[4 + i][j], 0, 0, 0);
        __builtin_amdgcn_s_setprio(0);
        __builtin_amdgcn_s_barrier();
    }

    __syncthreads();

    char* eb = (char*)&sm[0][0][0][0];
    const int mBb = (wr << 7) + r16;
    const int nBb = (wc << 6) + (u16 << 2);
#pragma unroll
    for (int i = 0; i < 8; ++i) {
        const int m = mBb + (i << 4);
        const int xm = (m & 15) << 4;
#pragma unroll
        for (int j = 0; j < 4; ++j) {
            const int nl = nBb + (j << 4);
            f32x4 bv = *(const f32x4*)(bias + n0 + nl);
            bf16x4 pk;
#pragma unroll
            for (int r = 0; r < 4; ++r) {
                float v = acc[i][j][r] + bv[r];
                if (RELU) v = fmaxf(v, 0.f);
                pk[r] = (bf16_t)v;
            }
            *(bf16x4*)(eb + m * 512 + ((nl << 1) ^ xm)) = pk;
        }
    }
    __syncthreads();
    const int cc = t & 31;
    const int rr = t >> 5;
#pragma unroll
    for (int rp = 0; rp < 16; ++rp) {
        const int m = (rp << 4) + rr;
        bf16x8 v = *(const bf16x8*)(eb + m * 512 + (((cc << 4) ^ ((m & 15) << 4)) & 511));
        *(bf16x8*)(C + (size_t)(m0 + m) * N + n0 + (cc << 3)) = v;
    }
}

// ---- fused head: hd = h2 @ Whead + bhead, probs + loss partial ------------
__global__ __launch_bounds__(256) void head_fused(
    const bf16_t* __restrict__ A, const bf16_t* __restrict__ BT,
    const float* __restrict__ bias, const int* __restrict__ data,
    float* __restrict__ probs_out, float* __restrict__ partials,
    int K, int row0)
{
    __shared__ __align__(16) bf16_t As[128 * 32];
    __shared__ __align__(16) bf16_t Bs[128 * 32];
    __shared__ float hdl[128 * 128];

    const int t    = threadIdx.x;
    const int lane = t & 63;
    const int w    = t >> 6;
    const int wm   = (w >> 1) << 6;
    const int wn   = (w & 1) << 6;
    const int m0l  = blockIdx.x << 7;

    const int srow  = t >> 2;
    const int skoff = (t & 3) << 3;

    const bf16_t* Ap = A  + (size_t)(m0l + srow) * K + skoff;
    const bf16_t* Bp = BT + (size_t)srow * K + skoff;
    const size_t rstep = (size_t)64 * K;

    bf16_t* lA0 = As + ((w << 6)      ) * 8;
    bf16_t* lA1 = As + ((w << 6) + 256) * 8;
    bf16_t* lB0 = Bs + ((w << 6)      ) * 8;
    bf16_t* lB1 = Bs + ((w << 6) + 256) * 8;

    f32x4 acc[4][4];
#pragma unroll
    for (int i = 0; i < 4; ++i)
#pragma unroll
        for (int j = 0; j < 4; ++j) acc[i][j] = (f32x4){0.f, 0.f, 0.f, 0.f};

    const int r16  = lane & 15;
    const int u16  = lane >> 4;
    const int kblk = u16 << 3;

    for (int k0 = 0; k0 < K; k0 += 32) {
        __syncthreads();
        gload16(Ap + k0,         lA0);
        gload16(Ap + rstep + k0, lA1);
        gload16(Bp + k0,         lB0);
        gload16(Bp + rstep + k0, lB1);
        __syncthreads();

        bf16x8 af[4], bfr[4];
#pragma unroll
        for (int i = 0; i < 4; ++i) {
            af[i]  = *(const bf16x8*)&As[(wm + (i << 4) + r16) * 32 + kblk];
            bfr[i] = *(const bf16x8*)&Bs[(wn + (i << 4) + r16) * 32 + kblk];
        }
#pragma unroll
        for (int i = 0; i < 4; ++i)
#pragma unroll
            for (int j = 0; j < 4; ++j)
                acc[i][j] = __builtin_amdgcn_mfma_f32_16x16x32_bf16(af[i], bfr[j], acc[i][j], 0, 0, 0);
    }

#pragma unroll
    for (int j = 0; j < 4; ++j) {
        const int col = wn + (j << 4) + r16;
        const float bv = bias[col];
#pragma unroll
        for (int i = 0; i < 4; ++i) {
            const int rb = wm + (i << 4) + (u16 << 2);
#pragma unroll
            for (int r = 0; r < 4; ++r)
                hdl[(rb + r) * 128 + col] = acc[i][j][r] + bv;
        }
    }
    __syncthreads();

    float lsum = 0.f;
    const int item = t & 15;
    const int cp   = 4 + (item & 3);
#pragma unroll
    for (int p = 0; p < 8; ++p) {
        const int row = (p << 4) + (t >> 4);
        const float* h = hdl + row * 128;
        const size_t grow = (size_t)row0 + m0l + row;

        const float f = h[item];
        float cumP[7];
        float cum = 0.f;
#pragma unroll
        for (int c = 0; c < 7; ++c) {
            if (c < cp) {
                float e = fmaxf(expf(h[16 + item * 7 + c]), EPSV);
                cum += e;
                float s = 1.f / (1.f + expf(f - cum));
                cumP[c] = fminf(fmaxf(s, EPSV), 1.f - EPSV);
            } else {
                cumP[c] = 0.f;
            }
        }
        float probs[8];
#pragma unroll
        for (int k = 0; k < 8; ++k) {
            float v;
            if (k < cp)       v = (k == 0) ? cumP[0] : (cumP[k] - cumP[k - 1]);
            else if (k == cp) v = 1.f - cumP[cp - 1];
            else              v = 1.f;
            probs[k] = fminf(fmaxf(v, EPSV), 1.f - EPSV);
        }
        float* dst = probs_out + (grow * 16 + item) * 8;
#pragma unroll
        for (int k = 0; k < 8; ++k) dst[k] = probs[k];

        const int d = data[grow * 16 + item];
        float g = probs[0];
#pragma unroll
        for (int k = 1; k < 8; ++k) g = (d == k) ? probs[k] : g;
        lsum += -logf(g);
    }

    __syncthreads();
    float* red = (float*)As;
    red[t] = lsum;
    __syncthreads();
#pragma unroll
    for (int s2 = 128; s2 > 0; s2 >>= 1) {
        if (t < s2) red[t] += red[t + s2];
        __syncthreads();
    }
    if (t == 0) partials[(row0 >> 7) + blockIdx.x] = red[0];
}

// ---------------- transpose weight K x N fp32 -> N x K bf16 ----------------
__global__ __launch_bounds__(256) void transpose_w(
    const float* __restrict__ in, bf16_t* __restrict__ out,
    int kshift, int N, int total)
{
    int idx = blockIdx.x * 256 + threadIdx.x;
    if (idx >= total) return;
    int n = idx >> kshift;
    int k = idx & ((1 << kshift) - 1);
    out[idx] = (bf16_t)in[(size_t)k * N + n];
}

// ---------------- pack head: WheadT (128 x 512) bf16 + bhead (128) f32 -----
__global__ __launch_bounds__(256) void pack_head(
    const float* __restrict__ Wf, const float* __restrict__ bfv,
    const float* __restrict__ Wk, const float* __restrict__ bk,
    bf16_t* __restrict__ WhT, float* __restrict__ bhead)
{
    int idx = blockIdx.x * 256 + threadIdx.x;
    int n = idx >> 9;
    int k = idx & 511;
    float v;
    if (n < 16) {
        v = Wf[k * 16 + n];
    } else {
        int m = n - 16;
        int i = m / 7, c = m % 7;
        v = Wk[(size_t)i * 3584 + (size_t)k * 7 + c];
    }
    WhT[idx] = (bf16_t)v;
    if (idx < 128) bhead[idx] = (idx < 16) ? bfv[idx] : bk[idx - 16];
}

__global__ __launch_bounds__(256) void reduce_loss(
    const float* __restrict__ partials, int n, float* __restrict__ out, float scale)
{
    __shared__ float red[256];
    float s = 0.f;
    for (int i = threadIdx.x; i < n; i += 256) s += partials[i];
    red[threadIdx.x] = s;
    __syncthreads();
    for (int k = 128; k > 0; k >>= 1) {
        if (threadIdx.x < k) red[threadIdx.x] += red[threadIdx.x + k];
        __syncthreads();
    }
    if (threadIdx.x == 0) out[0] = red[0] * scale;
}

extern "C" void kernel_launch(void* const* d_in, const int* in_sizes, int n_in,
                              void* d_out, int out_size, void* d_ws, size_t ws_size,
                              hipStream_t stream)
{
    const float* x   = (const float*)d_in[0];
    const int*   dat = (const int*)d_in[1];
    const float* W1  = (const float*)d_in[2];
    const float* b1  = (const float*)d_in[3];
    const float* W2  = (const float*)d_in[4];
    const float* b2  = (const float*)d_in[5];
    const float* Wf  = (const float*)d_in[6];
    const float* bfv = (const float*)d_in[7];
    const float* Wk  = (const float*)d_in[8];
    const float* bk  = (const float*)d_in[9];
    float* out = (float*)d_out;

    const int B = 65536, DIN = 512, H1 = 1024, H2 = 512;

    char* cur = (char*)d_ws;
    auto carve = [&](size_t bytes) {
        char* p = cur;
        cur += (bytes + 255) & ~(size_t)255;
        return p;
    };
    float*  partials = (float*)carve(4096 * 4);
    float*  bhead    = (float*)carve(512);
    bf16_t* W1T      = (bf16_t*)carve((size_t)H1 * DIN * 2);
    bf16_t* W2T      = (bf16_t*)carve((size_t)H2 * H1 * 2);
    bf16_t* WhT      = (bf16_t*)carve((size_t)128 * H2 * 2);

    // per-row slice bytes: h1 2048 + h2 1024 = 3072
    size_t used = (size_t)(cur - (char*)d_ws);
    size_t avail = (ws_size > used + 1024) ? (ws_size - used - 1024) : 0;
    int SLICE = 2048;
    const int cands[6] = {65536, 32768, 16384, 8192, 4096, 2048};
    for (int ci = 0; ci < 6; ++ci) {
        if ((size_t)cands[ci] * 3072 <= avail) { SLICE = cands[ci]; break; }
    }
    bf16_t* h1 = (bf16_t*)carve((size_t)SLICE * H1 * 2);
    bf16_t* h2 = (bf16_t*)carve((size_t)SLICE * H2 * 2);

    transpose_w<<<(H1 * DIN + 255) / 256, 256, 0, stream>>>(W1, W1T, 9,  H1, H1 * DIN);
    transpose_w<<<(H2 * H1 + 255) / 256, 256, 0, stream>>>(W2, W2T, 10, H2, H2 * H1);
    pack_head<<<256, 256, 0, stream>>>(Wf, bfv, Wk, bk, WhT, bhead);

    for (int r0 = 0; r0 < B; r0 += SLICE) {
        // layer 1: fused fp32->bf16 conversion inside the GEMM (no convert pass)
        gemm256f<true><<<(SLICE / 256) * (H1 / 256), 512, 0, stream>>>(
            x + (size_t)r0 * DIN, W1T, b1, h1, H1, DIN, H1 / 256);
        gemm256<true><<<(SLICE / 256) * (H2 / 256), 512, 0, stream>>>(
            h1, W2T, b2, h2, H2, H1, H2 / 256);
        head_fused<<<SLICE / 128, 256, 0, stream>>>(h2, WhT, bhead, dat, out + 1, partials, H2, r0);
    }
    reduce_loss<<<1, 256, 0, stream>>>(partials, B / 128, out, 1.0f / B);
}